// Round 1
// baseline (15610.350 us; speedup 1.0000x reference)
//
#include <hip/hip_runtime.h>

// ---------------------------------------------------------------------------
// VisualHead forward: fc1 -> masked BN -> relu+pe -> top2-of-4 gating ->
// 4x conv-FFN experts (KW=3, SAME) -> gated sum -> LN -> feat/feat_norm ->
// classifier -> log_softmax. All fp32 (round-0 correctness baseline).
// ---------------------------------------------------------------------------

namespace {

constexpr int kB = 16, kT = 512, kD = 1024, kFF = 2048, kE = 4, kCLS = 1200;
constexpr int kM = kB * kT;                    // 8192 token rows
constexpr size_t kBTD = (size_t)kM * kD;       // 8388608
constexpr size_t kBTC = (size_t)kM * kCLS;     // 9830400

// workspace layout (float elements)
constexpr size_t WS_H     = 0;                         // h / h' [M, D]
constexpr size_t WS_Y1    = WS_H + kBTD;               // y1 [M, FF]
constexpr size_t WS_MOE   = WS_Y1 + (size_t)kM * kFF;  // moe [M, D]
constexpr size_t WS_GATES = WS_MOE + kBTD;             // gates [M, E]
constexpr size_t WS_SUMS  = WS_GATES + (size_t)kM * kE;
constexpr size_t WS_SUMSQ = WS_SUMS + kD;
constexpr size_t WS_AA    = WS_SUMSQ + kD;             // bn scale
constexpr size_t WS_CC    = WS_AA + kD;                // bn shift
constexpr size_t WS_CNT   = WS_CC + kD;
constexpr size_t WS_IMP   = WS_CNT + 1;
constexpr size_t WS_FRAC  = WS_IMP + 4;
constexpr int WS_ZERON = (int)(WS_FRAC + 4 - WS_SUMS); // 4105 floats to zero

constexpr int BM = 64, BN = 64, BK = 16;

__device__ __forceinline__ float block_reduce_sum(float v, float* red) {
  const int tid = threadIdx.x;
  __syncthreads();                 // protect previous contents of red
  red[tid] = v;
  __syncthreads();
  for (int s = 128; s > 0; s >>= 1) {
    if (tid < s) red[tid] += red[tid + s];
    __syncthreads();
  }
  return red[0];
}

__device__ __forceinline__ float block_reduce_max(float v, float* red) {
  const int tid = threadIdx.x;
  __syncthreads();
  red[tid] = v;
  __syncthreads();
  for (int s = 128; s > 0; s >>= 1) {
    if (tid < s) red[tid] = fmaxf(red[tid], red[tid + s]);
    __syncthreads();
  }
  return red[0];
}

__global__ void k_zero(float* __restrict__ p, int n) {
  int i = blockIdx.x * 256 + threadIdx.x;
  if (i < n) p[i] = 0.f;
}

// C[m,n] = sum_k A[m,k] * Bw[n,k] + bias[n]; M % 64 == 0, K % 16 == 0.
__global__ __launch_bounds__(256) void k_gemm_bt(
    const float* __restrict__ A, const float* __restrict__ Bw,
    const float* __restrict__ bias, float* __restrict__ C,
    int M, int N, int K) {
  __shared__ float As[BK][BM];
  __shared__ float Bs[BK][BN];
  const int tx = threadIdx.x, ty = threadIdx.y;
  const int tid = ty * 16 + tx;
  const int m0 = blockIdx.y * BM, n0 = blockIdx.x * BN;
  const int lr = tid >> 2;          // 0..63
  const int lc = (tid & 3) * 4;     // 0,4,8,12
  const int nB = n0 + lr;
  const bool bok = nB < N;
  float acc[4][4] = {};
  for (int k0 = 0; k0 < K; k0 += BK) {
    float4 av = *reinterpret_cast<const float4*>(A + (size_t)(m0 + lr) * K + k0 + lc);
    float4 bv = make_float4(0.f, 0.f, 0.f, 0.f);
    if (bok) bv = *reinterpret_cast<const float4*>(Bw + (size_t)nB * K + k0 + lc);
    As[lc + 0][lr] = av.x; As[lc + 1][lr] = av.y; As[lc + 2][lr] = av.z; As[lc + 3][lr] = av.w;
    Bs[lc + 0][lr] = bv.x; Bs[lc + 1][lr] = bv.y; Bs[lc + 2][lr] = bv.z; Bs[lc + 3][lr] = bv.w;
    __syncthreads();
#pragma unroll
    for (int kk = 0; kk < BK; ++kk) {
      const float4 a = *reinterpret_cast<const float4*>(&As[kk][ty * 4]);
      const float4 b = *reinterpret_cast<const float4*>(&Bs[kk][tx * 4]);
      const float a4[4] = {a.x, a.y, a.z, a.w};
      const float b4[4] = {b.x, b.y, b.z, b.w};
#pragma unroll
      for (int i = 0; i < 4; ++i)
#pragma unroll
        for (int j = 0; j < 4; ++j) acc[i][j] = fmaf(a4[i], b4[j], acc[i][j]);
    }
    __syncthreads();
  }
#pragma unroll
  for (int i = 0; i < 4; ++i) {
    const int m = m0 + ty * 4 + i;
#pragma unroll
    for (int j = 0; j < 4; ++j) {
      const int n = n0 + tx * 4 + j;
      if (n < N) C[(size_t)m * N + n] = acc[i][j] + bias[n];
    }
  }
}

// y1[m,f] = relu(b1[f] + sum_{kk,d} h'[m+kk-1, d] * W[f, d, kk]); W: [FF, D, 3]
__global__ __launch_bounds__(256) void k_conv1(
    const float* __restrict__ Hp, const float* __restrict__ W,
    const float* __restrict__ bias, float* __restrict__ Y) {
  __shared__ float As[BK][BM];
  __shared__ float Bs[BK][BN];
  const int tx = threadIdx.x, ty = threadIdx.y;
  const int tid = ty * 16 + tx;
  const int m0 = blockIdx.y * BM, n0 = blockIdx.x * BN;
  const int lr = tid >> 2;
  const int lc = (tid & 3) * 4;
  const int mA = m0 + lr;
  const int tA = mA & (kT - 1);     // block never straddles batch (64 | 512)
  const int nB = n0 + lr;
  float acc[4][4] = {};
  for (int kk = 0; kk < 3; ++kk) {
    const int sh = kk - 1;
    const int ts = tA + sh;
    const bool valid = (ts >= 0) && (ts < kT);
    const float* wrow = W + (size_t)nB * (kD * 3) + kk;
    for (int k0 = 0; k0 < kD; k0 += BK) {
      float4 av = make_float4(0.f, 0.f, 0.f, 0.f);
      if (valid) av = *reinterpret_cast<const float4*>(Hp + (size_t)(mA + sh) * kD + k0 + lc);
      const float* wp = wrow + (size_t)(k0 + lc) * 3;
      As[lc + 0][lr] = av.x; As[lc + 1][lr] = av.y; As[lc + 2][lr] = av.z; As[lc + 3][lr] = av.w;
      Bs[lc + 0][lr] = wp[0]; Bs[lc + 1][lr] = wp[3]; Bs[lc + 2][lr] = wp[6]; Bs[lc + 3][lr] = wp[9];
      __syncthreads();
#pragma unroll
      for (int kk2 = 0; kk2 < BK; ++kk2) {
        const float4 a = *reinterpret_cast<const float4*>(&As[kk2][ty * 4]);
        const float4 b = *reinterpret_cast<const float4*>(&Bs[kk2][tx * 4]);
        const float a4[4] = {a.x, a.y, a.z, a.w};
        const float b4[4] = {b.x, b.y, b.z, b.w};
#pragma unroll
        for (int i = 0; i < 4; ++i)
#pragma unroll
          for (int j = 0; j < 4; ++j) acc[i][j] = fmaf(a4[i], b4[j], acc[i][j]);
      }
      __syncthreads();
    }
  }
#pragma unroll
  for (int i = 0; i < 4; ++i) {
    const int m = m0 + ty * 4 + i;
#pragma unroll
    for (int j = 0; j < 4; ++j) {
      const int n = n0 + tx * 4 + j;
      Y[(size_t)m * kFF + n] = fmaxf(acc[i][j] + bias[n], 0.f);
    }
  }
}

// moe[m,dc] (init/accum) += gates[m,e] * (b2[dc] + sum_{kk,f} y1[m+kk-1, f]*W[dc, f, kk])
__global__ __launch_bounds__(256) void k_conv2(
    const float* __restrict__ Y1, const float* __restrict__ W,
    const float* __restrict__ bias, const float* __restrict__ gates,
    int e, float* __restrict__ moe) {
  __shared__ float As[BK][BM];
  __shared__ float Bs[BK][BN];
  const int tx = threadIdx.x, ty = threadIdx.y;
  const int tid = ty * 16 + tx;
  const int m0 = blockIdx.y * BM, n0 = blockIdx.x * BN;
  const int lr = tid >> 2;
  const int lc = (tid & 3) * 4;
  const int mA = m0 + lr;
  const int tA = mA & (kT - 1);
  const int nB = n0 + lr;
  float acc[4][4] = {};
  for (int kk = 0; kk < 3; ++kk) {
    const int sh = kk - 1;
    const int ts = tA + sh;
    const bool valid = (ts >= 0) && (ts < kT);
    const float* wrow = W + (size_t)nB * (kFF * 3) + kk;
    for (int k0 = 0; k0 < kFF; k0 += BK) {
      float4 av = make_float4(0.f, 0.f, 0.f, 0.f);
      if (valid) av = *reinterpret_cast<const float4*>(Y1 + (size_t)(mA + sh) * kFF + k0 + lc);
      const float* wp = wrow + (size_t)(k0 + lc) * 3;
      As[lc + 0][lr] = av.x; As[lc + 1][lr] = av.y; As[lc + 2][lr] = av.z; As[lc + 3][lr] = av.w;
      Bs[lc + 0][lr] = wp[0]; Bs[lc + 1][lr] = wp[3]; Bs[lc + 2][lr] = wp[6]; Bs[lc + 3][lr] = wp[9];
      __syncthreads();
#pragma unroll
      for (int kk2 = 0; kk2 < BK; ++kk2) {
        const float4 a = *reinterpret_cast<const float4*>(&As[kk2][ty * 4]);
        const float4 b = *reinterpret_cast<const float4*>(&Bs[kk2][tx * 4]);
        const float a4[4] = {a.x, a.y, a.z, a.w};
        const float b4[4] = {b.x, b.y, b.z, b.w};
#pragma unroll
        for (int i = 0; i < 4; ++i)
#pragma unroll
          for (int j = 0; j < 4; ++j) acc[i][j] = fmaf(a4[i], b4[j], acc[i][j]);
      }
      __syncthreads();
    }
  }
#pragma unroll
  for (int i = 0; i < 4; ++i) {
    const int m = m0 + ty * 4 + i;
    const float g = gates[(size_t)m * kE + e];
#pragma unroll
    for (int j = 0; j < 4; ++j) {
      const int n = n0 + tx * 4 + j;
      const float val = acc[i][j] + bias[n];
      const size_t idx = (size_t)m * kD + n;
      moe[idx] = (e == 0 ? 0.f : moe[idx]) + g * val;
    }
  }
}

__global__ __launch_bounds__(256) void k_cnt(const int* __restrict__ mask,
                                             float* __restrict__ cnt) {
  __shared__ float red[256];
  const int i = blockIdx.x * 256 + threadIdx.x;
  float v = (float)mask[i];
  v = block_reduce_sum(v, red);
  if (threadIdx.x == 0) atomicAdd(cnt, v);
}

__global__ __launch_bounds__(256) void k_stats(const float* __restrict__ H,
                                               const int* __restrict__ mask,
                                               float* __restrict__ sums,
                                               float* __restrict__ sumsq) {
  const int ch = blockIdx.x * 256 + threadIdx.x;
  const int r0 = blockIdx.y * 256;
  float s = 0.f, q = 0.f;
  for (int r = r0; r < r0 + 256; ++r) {
    if (mask[r]) {
      const float v = H[(size_t)r * kD + ch];
      s += v;
      q += v * v;
    }
  }
  atomicAdd(&sums[ch], s);
  atomicAdd(&sumsq[ch], q);
}

__global__ __launch_bounds__(256) void k_finalize(
    const float* __restrict__ sums, const float* __restrict__ sumsq,
    const float* __restrict__ cntp, const float* __restrict__ bn_g,
    const float* __restrict__ bn_b, float* __restrict__ aa,
    float* __restrict__ cc) {
  const int d = blockIdx.x * 256 + threadIdx.x;
  const float cnt = fmaxf(*cntp, 1.f);
  const float mean = sums[d] / cnt;
  const float var = sumsq[d] / cnt - mean * mean;
  const float istd = rsqrtf(var + 1e-5f);
  const float a = bn_g[d] * istd;
  aa[d] = a;
  cc[d] = bn_b[d] - mean * a;
}

// per-row: apply masked BN, relu, +pe (in place); gate logits -> softmax/top2
__global__ __launch_bounds__(256) void k_norm_gate(
    float* __restrict__ H, const int* __restrict__ mask,
    const float* __restrict__ pe, const float* __restrict__ aa,
    const float* __restrict__ cc, const float* __restrict__ gw,
    float* __restrict__ gates, float* __restrict__ imp,
    float* __restrict__ frac) {
  __shared__ float red[256];
  __shared__ float glog[4];
  const int r = blockIdx.x;
  const int tid = threadIdx.x;
  const int t = r & (kT - 1);
  const bool mv = mask[r] != 0;
  float gl[4] = {0.f, 0.f, 0.f, 0.f};
#pragma unroll
  for (int j = 0; j < 4; ++j) {
    const int d = tid + j * 256;
    float v = H[(size_t)r * kD + d];
    if (mv) v = v * aa[d] + cc[d];
    v = fmaxf(v, 0.f) + pe[(size_t)t * kD + d];
    H[(size_t)r * kD + d] = v;
    const float4 g = *reinterpret_cast<const float4*>(gw + (size_t)d * 4);
    gl[0] += v * g.x; gl[1] += v * g.y; gl[2] += v * g.z; gl[3] += v * g.w;
  }
  for (int e = 0; e < 4; ++e) {
    const float s = block_reduce_sum(gl[e], red);
    if (tid == 0) glog[e] = s;
  }
  __syncthreads();
  if (tid == 0) {
    float lg[4] = {glog[0], glog[1], glog[2], glog[3]};
    const float mx = fmaxf(fmaxf(lg[0], lg[1]), fmaxf(lg[2], lg[3]));
    float ex[4], s = 0.f;
#pragma unroll
    for (int e = 0; e < 4; ++e) { ex[e] = expf(lg[e] - mx); s += ex[e]; }
    int i0 = 0;
    for (int e = 1; e < 4; ++e) if (lg[e] > lg[i0]) i0 = e;   // ties -> lowest idx
    int i1 = -1;
    for (int e = 0; e < 4; ++e) {
      if (e == i0) continue;
      if (i1 < 0 || lg[e] > lg[i1]) i1 = e;
    }
    const float g0 = 1.f / (1.f + expf(lg[i1] - lg[i0]));
    float gv[4] = {0.f, 0.f, 0.f, 0.f};
    gv[i0] = g0;
    gv[i1] = 1.f - g0;
    *reinterpret_cast<float4*>(gates + (size_t)r * 4) =
        make_float4(gv[0], gv[1], gv[2], gv[3]);
    const float inv_s = 1.f / s;
    atomicAdd(&imp[0], ex[0] * inv_s);
    atomicAdd(&imp[1], ex[1] * inv_s);
    atomicAdd(&imp[2], ex[2] * inv_s);
    atomicAdd(&imp[3], ex[3] * inv_s);
    atomicAdd(&frac[i0], 1.f);
    atomicAdd(&frac[i1], 1.f);
  }
}

__global__ __launch_bounds__(256) void k_ln(
    const float* __restrict__ moe, const float* __restrict__ g,
    const float* __restrict__ b, float* __restrict__ feat,
    float* __restrict__ featn) {
  __shared__ float red[256];
  const int r = blockIdx.x;
  const int tid = threadIdx.x;
  float v[4];
  float s = 0.f, q = 0.f;
#pragma unroll
  for (int j = 0; j < 4; ++j) {
    v[j] = moe[(size_t)r * kD + tid + j * 256];
    s += v[j];
    q += v[j] * v[j];
  }
  const float sum = block_reduce_sum(s, red);
  const float mu = sum * (1.f / kD);
  const float sq = block_reduce_sum(q, red);
  const float var = sq * (1.f / kD) - mu * mu;
  const float istd = rsqrtf(var + 1e-6f);
  float f[4];
  float fs = 0.f;
#pragma unroll
  for (int j = 0; j < 4; ++j) {
    const int d = tid + j * 256;
    f[j] = (v[j] - mu) * istd * g[d] + b[d];
    feat[(size_t)r * kD + d] = f[j];
    fs += f[j] * f[j];
  }
  const float nrm2 = block_reduce_sum(fs, red);
  const float scale = 1.f / fmaxf(sqrtf(nrm2), 1e-12f);
#pragma unroll
  for (int j = 0; j < 4; ++j) {
    const int d = tid + j * 256;
    featn[(size_t)r * kD + d] = f[j] * scale;
  }
}

__global__ __launch_bounds__(256) void k_softmax(
    const float* __restrict__ logits, float* __restrict__ logp,
    float* __restrict__ p) {
  __shared__ float red[256];
  const int r = blockIdx.x;
  const int tid = threadIdx.x;
  float lv[5];
  float mx = -1e30f;
#pragma unroll
  for (int j = 0; j < 5; ++j) {
    const int c = tid + j * 256;
    if (c < kCLS) {
      lv[j] = logits[(size_t)r * kCLS + c];
      mx = fmaxf(mx, lv[j]);
    }
  }
  mx = block_reduce_max(mx, red);
  float s = 0.f;
#pragma unroll
  for (int j = 0; j < 5; ++j) {
    const int c = tid + j * 256;
    if (c < kCLS) s += expf(lv[j] - mx);
  }
  s = block_reduce_sum(s, red);
  const float lse = mx + logf(s);
#pragma unroll
  for (int j = 0; j < 5; ++j) {
    const int c = tid + j * 256;
    if (c < kCLS) {
      const float lp = lv[j] - lse;
      logp[(size_t)r * kCLS + c] = lp;
      p[(size_t)r * kCLS + c] = expf(lp);
    }
  }
}

__global__ void k_aux(const float* __restrict__ imp,
                      const float* __restrict__ frac, float* __restrict__ out) {
  float s = 0.f;
  const float inv = 1.f / (float)kM;
#pragma unroll
  for (int e = 0; e < 4; ++e) s += (frac[e] * inv) * (imp[e] * inv);
  out[0] = (float)kE * s;
}

}  // namespace

extern "C" void kernel_launch(void* const* d_in, const int* in_sizes, int n_in,
                              void* d_out, int out_size, void* d_ws,
                              size_t ws_size, hipStream_t stream) {
  const float* x     = (const float*)d_in[0];
  const int*   mask  = (const int*)d_in[1];
  const float* fc1_w = (const float*)d_in[2];
  const float* fc1_b = (const float*)d_in[3];
  const float* bn_g  = (const float*)d_in[4];
  const float* bn_b  = (const float*)d_in[5];
  const float* pe    = (const float*)d_in[6];
  const float* gw    = (const float*)d_in[7];
  const float* ew1   = (const float*)d_in[8];
  const float* eb1   = (const float*)d_in[9];
  const float* ew2   = (const float*)d_in[10];
  const float* eb2   = (const float*)d_in[11];
  const float* ln_g  = (const float*)d_in[12];
  const float* ln_b  = (const float*)d_in[13];
  const float* out_w = (const float*)d_in[14];
  const float* out_b = (const float*)d_in[15];

  float* ws = (float*)d_ws;
  float* H     = ws + WS_H;
  float* Y1    = ws + WS_Y1;
  float* MOE   = ws + WS_MOE;
  float* GATES = ws + WS_GATES;
  float* SUMS  = ws + WS_SUMS;
  float* SUMSQ = ws + WS_SUMSQ;
  float* AA    = ws + WS_AA;
  float* CC    = ws + WS_CC;
  float* CNT   = ws + WS_CNT;
  float* IMP   = ws + WS_IMP;
  float* FRAC  = ws + WS_FRAC;

  float* outf   = (float*)d_out;
  float* feat   = outf;
  float* featn  = outf + kBTD;
  float* logits = outf + 2 * kBTD;
  float* logp   = logits + kBTC;
  float* pprob  = logp + kBTC;
  float* aux    = pprob + kBTC;

  const dim3 blk2(16, 16);

  k_zero<<<dim3((WS_ZERON + 255) / 256), 256, 0, stream>>>(SUMS, WS_ZERON);
  // fc1: h = x @ fc1_w^T + b   [8192,1024]x[1024,1024]
  k_gemm_bt<<<dim3(kD / BN, kM / BM), blk2, 0, stream>>>(x, fc1_w, fc1_b, H,
                                                         kM, kD, kD);
  k_cnt<<<dim3(kM / 256), 256, 0, stream>>>(mask, CNT);
  k_stats<<<dim3(kD / 256, kM / 256), 256, 0, stream>>>(H, mask, SUMS, SUMSQ);
  k_finalize<<<dim3(kD / 256), 256, 0, stream>>>(SUMS, SUMSQ, CNT, bn_g, bn_b,
                                                 AA, CC);
  k_norm_gate<<<dim3(kM), 256, 0, stream>>>(H, mask, pe, AA, CC, gw, GATES,
                                            IMP, FRAC);
  for (int e = 0; e < kE; ++e) {
    k_conv1<<<dim3(kFF / BN, kM / BM), blk2, 0, stream>>>(
        H, ew1 + (size_t)e * kFF * kD * 3, eb1 + (size_t)e * kFF, Y1);
    k_conv2<<<dim3(kD / BN, kM / BM), blk2, 0, stream>>>(
        Y1, ew2 + (size_t)e * kD * kFF * 3, eb2 + (size_t)e * kD, GATES, e,
        MOE);
  }
  k_ln<<<dim3(kM), 256, 0, stream>>>(MOE, ln_g, ln_b, feat, featn);
  // classifier: logits = feat @ out_w^T + out_b  [8192,1200]
  k_gemm_bt<<<dim3((kCLS + BN - 1) / BN, kM / BM), blk2, 0, stream>>>(
      feat, out_w, out_b, logits, kM, kCLS, kD);
  k_softmax<<<dim3(kM), 256, 0, stream>>>(logits, logp, pprob);
  k_aux<<<1, 1, 0, stream>>>(IMP, FRAC, aux);
}

// Round 2
// 2799.152 us; speedup vs baseline: 5.5768x; 5.5768x over previous
//
#include <hip/hip_runtime.h>
#include <hip/hip_bf16.h>

// ---------------------------------------------------------------------------
// VisualHead forward. Round 2: conv-FFN experts as bf16 MFMA implicit GEMM
// (m97 structure: 128x128 tile, BK=32, global_load_lds width=16,
// mfma_f32_16x16x32_bf16). KW=3 SAME conv = 3 shifted GEMMs over padded
// activations (zero sentinel rows at t=-1 and t=T per batch).
// fc1 / classifier remain fp32 tiled GEMM this round.
// ---------------------------------------------------------------------------

namespace {

constexpr int kB = 16, kT = 512, kD = 1024, kFF = 2048, kE = 4, kCLS = 1200;
constexpr int kM = kB * kT;                    // 8192 token rows
constexpr int kTP = kT + 2;                    // padded seq len
constexpr size_t kBTD = (size_t)kM * kD;
constexpr size_t kBTC = (size_t)kM * kCLS;

// workspace layout (float-element units)
constexpr size_t WS_H     = 0;                                   // fc1 out fp32 [M,D]; later aliased as MOE accum
constexpr size_t WS_HPAD  = WS_H + kBTD;                         // bf16 [B*kTP, D]   (4,210,688 f)
constexpr size_t WS_Y1P   = WS_HPAD + (size_t)kB * kTP * kD / 2; // bf16 [B*kTP, FF]  (8,421,376 f)
constexpr size_t WS_W1T   = WS_Y1P + (size_t)kB * kTP * kFF / 2; // bf16 [3,FF,D]     (3,145,728 f)
constexpr size_t WS_W2T   = WS_W1T + (size_t)3 * kFF * kD / 2;   // bf16 [3,D,FF]     (3,145,728 f)
constexpr size_t WS_GATES = WS_W2T + (size_t)3 * kD * kFF / 2;   // fp32 [M,4]
constexpr size_t WS_SUMS  = WS_GATES + (size_t)kM * kE;
constexpr size_t WS_SUMSQ = WS_SUMS + kD;
constexpr size_t WS_AA    = WS_SUMSQ + kD;
constexpr size_t WS_CC    = WS_AA + kD;
constexpr size_t WS_CNT   = WS_CC + kD;
constexpr size_t WS_IMP   = WS_CNT + 1;
constexpr size_t WS_FRAC  = WS_IMP + 4;
constexpr int WS_ZERON = (int)(WS_FRAC + 4 - WS_SUMS);

typedef __attribute__((ext_vector_type(8))) short short8;
typedef __attribute__((ext_vector_type(4))) float f32x4;

#define GLOBAL_LOAD_LDS16(gp, lp)                                          \
  __builtin_amdgcn_global_load_lds(                                        \
      (const __attribute__((address_space(1))) void*)(gp),                 \
      (__attribute__((address_space(3))) void*)(lp), 16, 0, 0)

__device__ __forceinline__ float block_reduce_sum(float v, float* red) {
  const int tid = threadIdx.x;
  __syncthreads();
  red[tid] = v;
  __syncthreads();
  for (int s = 128; s > 0; s >>= 1) {
    if (tid < s) red[tid] += red[tid + s];
    __syncthreads();
  }
  return red[0];
}

__device__ __forceinline__ float block_reduce_max(float v, float* red) {
  const int tid = threadIdx.x;
  __syncthreads();
  red[tid] = v;
  __syncthreads();
  for (int s = 128; s > 0; s >>= 1) {
    if (tid < s) red[tid] = fmaxf(red[tid], red[tid + s]);
    __syncthreads();
  }
  return red[0];
}

__global__ void k_zero(float* __restrict__ p, int n) {
  int i = blockIdx.x * 256 + threadIdx.x;
  if (i < n) p[i] = 0.f;
}

// zero sentinel rows (t=-1 and t=T) of Hpad and Y1pad
__global__ void k_zero_bnd(__hip_bfloat16* __restrict__ Hpad,
                           __hip_bfloat16* __restrict__ Y1pad) {
  const int b = blockIdx.x >> 1;
  const int row = b * kTP + ((blockIdx.x & 1) ? (kTP - 1) : 0);
  const __hip_bfloat16 z = __float2bfloat16(0.f);
  for (int d = threadIdx.x; d < kD; d += 256) Hpad[(size_t)row * kD + d] = z;
  for (int d = threadIdx.x; d < kFF; d += 256) Y1pad[(size_t)row * kFF + d] = z;
}

// weight transpose+cast: src [O][I][3] fp32 -> dst [3][O][I] bf16 (n = O*I)
__global__ __launch_bounds__(256) void k_wt(const float* __restrict__ src,
                                            __hip_bfloat16* __restrict__ dst,
                                            int n) {
  const int i = blockIdx.x * 256 + threadIdx.x;
  if (i >= n) return;
  const float* s = src + (size_t)i * 3;
  dst[i] = __float2bfloat16(s[0]);
  dst[(size_t)n + i] = __float2bfloat16(s[1]);
  dst[(size_t)2 * n + i] = __float2bfloat16(s[2]);
}

// ----- fp32 tiled GEMM (fc1 / classifier): C = A @ B^T + bias -----
constexpr int BM = 64, BN = 64, BK = 16;
__global__ __launch_bounds__(256) void k_gemm_bt(
    const float* __restrict__ A, const float* __restrict__ Bw,
    const float* __restrict__ bias, float* __restrict__ C,
    int M, int N, int K) {
  __shared__ float As[BK][BM];
  __shared__ float Bs[BK][BN];
  const int tx = threadIdx.x, ty = threadIdx.y;
  const int tid = ty * 16 + tx;
  const int m0 = blockIdx.y * BM, n0 = blockIdx.x * BN;
  const int lr = tid >> 2;
  const int lc = (tid & 3) * 4;
  const int nB = n0 + lr;
  const bool bok = nB < N;
  float acc[4][4] = {};
  for (int k0 = 0; k0 < K; k0 += BK) {
    float4 av = *reinterpret_cast<const float4*>(A + (size_t)(m0 + lr) * K + k0 + lc);
    float4 bv = make_float4(0.f, 0.f, 0.f, 0.f);
    if (bok) bv = *reinterpret_cast<const float4*>(Bw + (size_t)nB * K + k0 + lc);
    As[lc + 0][lr] = av.x; As[lc + 1][lr] = av.y; As[lc + 2][lr] = av.z; As[lc + 3][lr] = av.w;
    Bs[lc + 0][lr] = bv.x; Bs[lc + 1][lr] = bv.y; Bs[lc + 2][lr] = bv.z; Bs[lc + 3][lr] = bv.w;
    __syncthreads();
#pragma unroll
    for (int kk = 0; kk < BK; ++kk) {
      const float4 a = *reinterpret_cast<const float4*>(&As[kk][ty * 4]);
      const float4 b = *reinterpret_cast<const float4*>(&Bs[kk][tx * 4]);
      const float a4[4] = {a.x, a.y, a.z, a.w};
      const float b4[4] = {b.x, b.y, b.z, b.w};
#pragma unroll
      for (int i = 0; i < 4; ++i)
#pragma unroll
        for (int j = 0; j < 4; ++j) acc[i][j] = fmaf(a4[i], b4[j], acc[i][j]);
    }
    __syncthreads();
  }
#pragma unroll
  for (int i = 0; i < 4; ++i) {
    const int m = m0 + ty * 4 + i;
#pragma unroll
    for (int j = 0; j < 4; ++j) {
      const int n = n0 + tx * 4 + j;
      if (n < N) C[(size_t)m * N + n] = acc[i][j] + bias[n];
    }
  }
}

// ----- MFMA conv kernels -----
// conv1: Y1pad[., n] = relu(b1[n] + sum_kk Hpad_shift(kk) @ W1T[kk]^T)
__global__ __launch_bounds__(256) void k_conv1_mfma(
    const __hip_bfloat16* __restrict__ Hpad,   // [B*kTP, D]
    const __hip_bfloat16* __restrict__ W1T,    // [3, FF, D]
    const float* __restrict__ b1,              // [FF]
    __hip_bfloat16* __restrict__ Y1pad) {      // [B*kTP, FF]
  __shared__ __align__(16) __hip_bfloat16 As[128 * 32];
  __shared__ __align__(16) __hip_bfloat16 Bs[128 * 32];
  const int tid = threadIdx.x;
  const int m0 = blockIdx.y * 128;
  const int n0 = blockIdx.x * 128;
  const int b = m0 >> 9;
  const int t0 = m0 & (kT - 1);
  const int arow0 = b * kTP + t0;    // + kk = Hpad row of tap kk, local row 0
  const int w = tid >> 6, lane = tid & 63;
  const int wm = (w >> 1) * 64, wn = (w & 1) * 64;
  f32x4 acc[4][4] = {};
  const int fr = lane & 15, fc = (lane >> 4) * 8;
  for (int kk = 0; kk < 3; ++kk) {
    const __hip_bfloat16* Ab = Hpad + (size_t)(arow0 + kk) * kD;
    const __hip_bfloat16* Bb = W1T + (size_t)kk * kFF * kD + (size_t)n0 * kD;
    for (int k0 = 0; k0 < kD; k0 += 32) {
      __syncthreads();
#pragma unroll
      for (int r = 0; r < 2; ++r) {
        const int idx = r * 256 + tid;
        const int row = idx >> 2, cg = (idx & 3) * 8;
        GLOBAL_LOAD_LDS16(Ab + (size_t)row * kD + k0 + cg, &As[idx * 8]);
        GLOBAL_LOAD_LDS16(Bb + (size_t)row * kD + k0 + cg, &Bs[idx * 8]);
      }
      __syncthreads();
      short8 af[4], bf[4];
#pragma unroll
      for (int i = 0; i < 4; ++i) {
        af[i] = *reinterpret_cast<const short8*>(&As[(wm + i * 16 + fr) * 32 + fc]);
        bf[i] = *reinterpret_cast<const short8*>(&Bs[(wn + i * 16 + fr) * 32 + fc]);
      }
#pragma unroll
      for (int i = 0; i < 4; ++i)
#pragma unroll
        for (int j = 0; j < 4; ++j)
          acc[i][j] = __builtin_amdgcn_mfma_f32_16x16x32_bf16(af[i], bf[j], acc[i][j], 0, 0, 0);
    }
  }
  const int orow0 = b * kTP + t0 + 1;
  const int cr = (lane >> 4) * 4, cc = lane & 15;
#pragma unroll
  for (int i = 0; i < 4; ++i) {
#pragma unroll
    for (int r = 0; r < 4; ++r) {
      const int lr = wm + i * 16 + cr + r;
#pragma unroll
      for (int j = 0; j < 4; ++j) {
        const int gc = n0 + wn + j * 16 + cc;
        const float v = acc[i][j][r] + b1[gc];
        Y1pad[(size_t)(orow0 + lr) * kFF + gc] = __float2bfloat16(fmaxf(v, 0.f));
      }
    }
  }
}

// conv2: MOE[m, n] (+)= gates[m,e] * (b2[n] + sum_kk Y1pad_shift(kk) @ W2T[kk]^T)
__global__ __launch_bounds__(256) void k_conv2_mfma(
    const __hip_bfloat16* __restrict__ Y1pad,  // [B*kTP, FF]
    const __hip_bfloat16* __restrict__ W2T,    // [3, D, FF]
    const float* __restrict__ b2,              // [D]
    const float* __restrict__ gates,           // [M, 4]
    int e, float* __restrict__ moe) {          // [M, D]
  __shared__ __align__(16) __hip_bfloat16 As[128 * 32];
  __shared__ __align__(16) __hip_bfloat16 Bs[128 * 32];
  const int tid = threadIdx.x;
  const int m0 = blockIdx.y * 128;
  const int n0 = blockIdx.x * 128;
  const int b = m0 >> 9;
  const int t0 = m0 & (kT - 1);
  const int arow0 = b * kTP + t0;
  const int w = tid >> 6, lane = tid & 63;
  const int wm = (w >> 1) * 64, wn = (w & 1) * 64;
  f32x4 acc[4][4] = {};
  const int fr = lane & 15, fc = (lane >> 4) * 8;
  for (int kk = 0; kk < 3; ++kk) {
    const __hip_bfloat16* Ab = Y1pad + (size_t)(arow0 + kk) * kFF;
    const __hip_bfloat16* Bb = W2T + (size_t)kk * kD * kFF + (size_t)n0 * kFF;
    for (int k0 = 0; k0 < kFF; k0 += 32) {
      __syncthreads();
#pragma unroll
      for (int r = 0; r < 2; ++r) {
        const int idx = r * 256 + tid;
        const int row = idx >> 2, cg = (idx & 3) * 8;
        GLOBAL_LOAD_LDS16(Ab + (size_t)row * kFF + k0 + cg, &As[idx * 8]);
        GLOBAL_LOAD_LDS16(Bb + (size_t)row * kFF + k0 + cg, &Bs[idx * 8]);
      }
      __syncthreads();
      short8 af[4], bf[4];
#pragma unroll
      for (int i = 0; i < 4; ++i) {
        af[i] = *reinterpret_cast<const short8*>(&As[(wm + i * 16 + fr) * 32 + fc]);
        bf[i] = *reinterpret_cast<const short8*>(&Bs[(wn + i * 16 + fr) * 32 + fc]);
      }
#pragma unroll
      for (int i = 0; i < 4; ++i)
#pragma unroll
        for (int j = 0; j < 4; ++j)
          acc[i][j] = __builtin_amdgcn_mfma_f32_16x16x32_bf16(af[i], bf[j], acc[i][j], 0, 0, 0);
    }
  }
  const int cr = (lane >> 4) * 4, cc = lane & 15;
#pragma unroll
  for (int i = 0; i < 4; ++i) {
#pragma unroll
    for (int r = 0; r < 4; ++r) {
      const int lr = wm + i * 16 + cr + r;
      const int m = m0 + lr;
      const float g = gates[(size_t)m * kE + e];
#pragma unroll
      for (int j = 0; j < 4; ++j) {
        const int gc = n0 + wn + j * 16 + cc;
        const float v = acc[i][j][r] + b2[gc];
        const size_t idx = (size_t)m * kD + gc;
        moe[idx] = (e == 0 ? 0.f : moe[idx]) + g * v;
      }
    }
  }
}

// ----- small kernels -----
__global__ __launch_bounds__(256) void k_cnt(const int* __restrict__ mask,
                                             float* __restrict__ cnt) {
  __shared__ float red[256];
  const int i = blockIdx.x * 256 + threadIdx.x;
  float v = (float)mask[i];
  v = block_reduce_sum(v, red);
  if (threadIdx.x == 0) atomicAdd(cnt, v);
}

__global__ __launch_bounds__(256) void k_stats(const float* __restrict__ H,
                                               const int* __restrict__ mask,
                                               float* __restrict__ sums,
                                               float* __restrict__ sumsq) {
  const int ch = blockIdx.x * 256 + threadIdx.x;
  const int r0 = blockIdx.y * 256;
  float s = 0.f, q = 0.f;
  for (int r = r0; r < r0 + 256; ++r) {
    if (mask[r]) {
      const float v = H[(size_t)r * kD + ch];
      s += v;
      q += v * v;
    }
  }
  atomicAdd(&sums[ch], s);
  atomicAdd(&sumsq[ch], q);
}

__global__ __launch_bounds__(256) void k_finalize(
    const float* __restrict__ sums, const float* __restrict__ sumsq,
    const float* __restrict__ cntp, const float* __restrict__ bn_g,
    const float* __restrict__ bn_b, float* __restrict__ aa,
    float* __restrict__ cc) {
  const int d = blockIdx.x * 256 + threadIdx.x;
  const float cnt = fmaxf(*cntp, 1.f);
  const float mean = sums[d] / cnt;
  const float var = sumsq[d] / cnt - mean * mean;
  const float istd = rsqrtf(var + 1e-5f);
  const float a = bn_g[d] * istd;
  aa[d] = a;
  cc[d] = bn_b[d] - mean * a;
}

// masked BN + relu + pe -> Hpad (bf16); gate softmax/top2 -> gates, imp, frac
__global__ __launch_bounds__(256) void k_norm_gate(
    const float* __restrict__ H, const int* __restrict__ mask,
    const float* __restrict__ pe, const float* __restrict__ aa,
    const float* __restrict__ cc, const float* __restrict__ gw,
    __hip_bfloat16* __restrict__ Hpad, float* __restrict__ gates,
    float* __restrict__ imp, float* __restrict__ frac) {
  __shared__ float red[256];
  __shared__ float glog[4];
  const int r = blockIdx.x;
  const int tid = threadIdx.x;
  const int b = r >> 9;
  const int t = r & (kT - 1);
  const bool mv = mask[r] != 0;
  const size_t orow = (size_t)(b * kTP + t + 1) * kD;
  float gl[4] = {0.f, 0.f, 0.f, 0.f};
#pragma unroll
  for (int j = 0; j < 4; ++j) {
    const int d = tid + j * 256;
    float v = H[(size_t)r * kD + d];
    if (mv) v = v * aa[d] + cc[d];
    v = fmaxf(v, 0.f) + pe[(size_t)t * kD + d];
    Hpad[orow + d] = __float2bfloat16(v);
    const float4 g = *reinterpret_cast<const float4*>(gw + (size_t)d * 4);
    gl[0] += v * g.x; gl[1] += v * g.y; gl[2] += v * g.z; gl[3] += v * g.w;
  }
  for (int e = 0; e < 4; ++e) {
    const float s = block_reduce_sum(gl[e], red);
    if (tid == 0) glog[e] = s;
  }
  __syncthreads();
  if (tid == 0) {
    float lg[4] = {glog[0], glog[1], glog[2], glog[3]};
    const float mx = fmaxf(fmaxf(lg[0], lg[1]), fmaxf(lg[2], lg[3]));
    float ex[4], s = 0.f;
#pragma unroll
    for (int e = 0; e < 4; ++e) { ex[e] = expf(lg[e] - mx); s += ex[e]; }
    int i0 = 0;
    for (int e = 1; e < 4; ++e) if (lg[e] > lg[i0]) i0 = e;
    int i1 = -1;
    for (int e = 0; e < 4; ++e) {
      if (e == i0) continue;
      if (i1 < 0 || lg[e] > lg[i1]) i1 = e;
    }
    const float g0 = 1.f / (1.f + expf(lg[i1] - lg[i0]));
    float gv[4] = {0.f, 0.f, 0.f, 0.f};
    gv[i0] = g0;
    gv[i1] = 1.f - g0;
    *reinterpret_cast<float4*>(gates + (size_t)r * 4) =
        make_float4(gv[0], gv[1], gv[2], gv[3]);
    const float inv_s = 1.f / s;
    atomicAdd(&imp[0], ex[0] * inv_s);
    atomicAdd(&imp[1], ex[1] * inv_s);
    atomicAdd(&imp[2], ex[2] * inv_s);
    atomicAdd(&imp[3], ex[3] * inv_s);
    atomicAdd(&frac[i0], 1.f);
    atomicAdd(&frac[i1], 1.f);
  }
}

__global__ __launch_bounds__(256) void k_ln(
    const float* __restrict__ moe, const float* __restrict__ g,
    const float* __restrict__ b, float* __restrict__ feat,
    float* __restrict__ featn) {
  __shared__ float red[256];
  const int r = blockIdx.x;
  const int tid = threadIdx.x;
  float v[4];
  float s = 0.f, q = 0.f;
#pragma unroll
  for (int j = 0; j < 4; ++j) {
    v[j] = moe[(size_t)r * kD + tid + j * 256];
    s += v[j];
    q += v[j] * v[j];
  }
  const float sum = block_reduce_sum(s, red);
  const float mu = sum * (1.f / kD);
  const float sq = block_reduce_sum(q, red);
  const float var = sq * (1.f / kD) - mu * mu;
  const float istd = rsqrtf(var + 1e-6f);
  float f[4];
  float fs = 0.f;
#pragma unroll
  for (int j = 0; j < 4; ++j) {
    const int d = tid + j * 256;
    f[j] = (v[j] - mu) * istd * g[d] + b[d];
    feat[(size_t)r * kD + d] = f[j];
    fs += f[j] * f[j];
  }
  const float nrm2 = block_reduce_sum(fs, red);
  const float scale = 1.f / fmaxf(sqrtf(nrm2), 1e-12f);
#pragma unroll
  for (int j = 0; j < 4; ++j) {
    const int d = tid + j * 256;
    featn[(size_t)r * kD + d] = f[j] * scale;
  }
}

__global__ __launch_bounds__(256) void k_softmax(
    const float* __restrict__ logits, float* __restrict__ logp,
    float* __restrict__ p) {
  __shared__ float red[256];
  const int r = blockIdx.x;
  const int tid = threadIdx.x;
  float lv[5];
  float mx = -1e30f;
#pragma unroll
  for (int j = 0; j < 5; ++j) {
    const int c = tid + j * 256;
    if (c < kCLS) {
      lv[j] = logits[(size_t)r * kCLS + c];
      mx = fmaxf(mx, lv[j]);
    }
  }
  mx = block_reduce_max(mx, red);
  float s = 0.f;
#pragma unroll
  for (int j = 0; j < 5; ++j) {
    const int c = tid + j * 256;
    if (c < kCLS) s += expf(lv[j] - mx);
  }
  s = block_reduce_sum(s, red);
  const float lse = mx + logf(s);
#pragma unroll
  for (int j = 0; j < 5; ++j) {
    const int c = tid + j * 256;
    if (c < kCLS) {
      const float lp = lv[j] - lse;
      logp[(size_t)r * kCLS + c] = lp;
      p[(size_t)r * kCLS + c] = expf(lp);
    }
  }
}

__global__ void k_aux(const float* __restrict__ imp,
                      const float* __restrict__ frac, float* __restrict__ out) {
  float s = 0.f;
  const float inv = 1.f / (float)kM;
#pragma unroll
  for (int e = 0; e < 4; ++e) s += (frac[e] * inv) * (imp[e] * inv);
  out[0] = (float)kE * s;
}

}  // namespace

extern "C" void kernel_launch(void* const* d_in, const int* in_sizes, int n_in,
                              void* d_out, int out_size, void* d_ws,
                              size_t ws_size, hipStream_t stream) {
  const float* x     = (const float*)d_in[0];
  const int*   mask  = (const int*)d_in[1];
  const float* fc1_w = (const float*)d_in[2];
  const float* fc1_b = (const float*)d_in[3];
  const float* bn_g  = (const float*)d_in[4];
  const float* bn_b  = (const float*)d_in[5];
  const float* pe    = (const float*)d_in[6];
  const float* gw    = (const float*)d_in[7];
  const float* ew1   = (const float*)d_in[8];
  const float* eb1   = (const float*)d_in[9];
  const float* ew2   = (const float*)d_in[10];
  const float* eb2   = (const float*)d_in[11];
  const float* ln_g  = (const float*)d_in[12];
  const float* ln_b  = (const float*)d_in[13];
  const float* out_w = (const float*)d_in[14];
  const float* out_b = (const float*)d_in[15];

  float* ws = (float*)d_ws;
  float* H     = ws + WS_H;            // fc1 out; later MOE accumulator
  __hip_bfloat16* HPAD  = (__hip_bfloat16*)(ws + WS_HPAD);
  __hip_bfloat16* Y1PAD = (__hip_bfloat16*)(ws + WS_Y1P);
  __hip_bfloat16* W1T   = (__hip_bfloat16*)(ws + WS_W1T);
  __hip_bfloat16* W2T   = (__hip_bfloat16*)(ws + WS_W2T);
  float* GATES = ws + WS_GATES;
  float* SUMS  = ws + WS_SUMS;
  float* SUMSQ = ws + WS_SUMSQ;
  float* AA    = ws + WS_AA;
  float* CC    = ws + WS_CC;
  float* CNT   = ws + WS_CNT;
  float* IMP   = ws + WS_IMP;
  float* FRAC  = ws + WS_FRAC;
  float* MOE   = H;                    // alias: H is dead once Hpad is built

  float* outf   = (float*)d_out;
  float* feat   = outf;
  float* featn  = outf + kBTD;
  float* logits = outf + 2 * kBTD;
  float* logp   = logits + kBTC;
  float* pprob  = logp + kBTC;
  float* aux    = pprob + kBTC;

  const dim3 blk2(16, 16);

  k_zero<<<dim3((WS_ZERON + 255) / 256), 256, 0, stream>>>(SUMS, WS_ZERON);
  k_zero_bnd<<<dim3(2 * kB), 256, 0, stream>>>(HPAD, Y1PAD);
  // fc1: h = x @ fc1_w^T + b
  k_gemm_bt<<<dim3(kD / BN, kM / BM), blk2, 0, stream>>>(x, fc1_w, fc1_b, H,
                                                         kM, kD, kD);
  k_cnt<<<dim3(kM / 256), 256, 0, stream>>>(mask, CNT);
  k_stats<<<dim3(kD / 256, kM / 256), 256, 0, stream>>>(H, mask, SUMS, SUMSQ);
  k_finalize<<<dim3(kD / 256), 256, 0, stream>>>(SUMS, SUMSQ, CNT, bn_g, bn_b,
                                                 AA, CC);
  k_norm_gate<<<dim3(kM), 256, 0, stream>>>(H, mask, pe, AA, CC, gw, HPAD,
                                            GATES, IMP, FRAC);
  for (int e = 0; e < kE; ++e) {
    k_wt<<<dim3((kFF * kD + 255) / 256), 256, 0, stream>>>(
        ew1 + (size_t)e * kFF * kD * 3, W1T, kFF * kD);
    k_wt<<<dim3((kD * kFF + 255) / 256), 256, 0, stream>>>(
        ew2 + (size_t)e * kD * kFF * 3, W2T, kD * kFF);
    k_conv1_mfma<<<dim3(kFF / 128, kM / 128), 256, 0, stream>>>(
        HPAD, W1T, eb1 + (size_t)e * kFF, Y1PAD);
    k_conv2_mfma<<<dim3(kD / 128, kM / 128), 256, 0, stream>>>(
        Y1PAD, W2T, eb2 + (size_t)e * kD, GATES, e, MOE);
  }
  k_ln<<<dim3(kM), 256, 0, stream>>>(MOE, ln_g, ln_b, feat, featn);
  k_gemm_bt<<<dim3((kCLS + BN - 1) / BN, kM / BM), blk2, 0, stream>>>(
      feat, out_w, out_b, logits, kM, kCLS, kD);
  k_softmax<<<dim3(kM), 256, 0, stream>>>(logits, logp, pprob);
  k_aux<<<1, 1, 0, stream>>>(IMP, FRAC, aux);
}

// Round 3
// 1794.720 us; speedup vs baseline: 8.6979x; 1.5597x over previous
//
#include <hip/hip_runtime.h>
#include <hip/hip_bf16.h>

// ---------------------------------------------------------------------------
// VisualHead forward. Round 3:
//  - conv-FFN experts: bf16 MFMA implicit GEMM (m97 structure), unchanged.
//  - fc1: split-bf16 MFMA (x=hi+lo, w=hi+lo; hi*hi+lo*hi+hi*lo) so the
//    discrete top-2 gating decisions stay fp32-exact (~2^-17 residual).
//  - classifier: plain bf16 MFMA over bf16 feat and padded out_w.
//  - k_norm_gate: no global atomics; probs stored per-row, k_aux reduces.
// ---------------------------------------------------------------------------

namespace {

constexpr int kB = 16, kT = 512, kD = 1024, kFF = 2048, kE = 4, kCLS = 1200;
constexpr int kM = kB * kT;                    // 8192
constexpr int kTP = kT + 2;                    // padded seq len
constexpr int kCLSP = 1280;                    // padded classifier rows
constexpr size_t kBTD = (size_t)kM * kD;
constexpr size_t kBTC = (size_t)kM * kCLS;

// workspace layout (float-element units)
constexpr size_t WS_H     = 0;                                   // fp32 [M,D]; later MOE accum
constexpr size_t WS_HPAD  = WS_H + kBTD;                         // bf16 [B*kTP, D]
constexpr size_t WS_Y1P   = WS_HPAD + (size_t)kB * kTP * kD / 2; // bf16 [B*kTP, FF]; aliased: XHI/XLO (fc1), FEATB (epilogue)
constexpr size_t WS_W1T   = WS_Y1P + (size_t)kB * kTP * kFF / 2; // bf16 [3,FF,D]
constexpr size_t WS_W2T   = WS_W1T + (size_t)3 * kFF * kD / 2;   // bf16 [3,D,FF]
constexpr size_t WS_GATES = WS_W2T + (size_t)3 * kD * kFF / 2;   // fp32 [M,4]
constexpr size_t WS_PROBS = WS_GATES + (size_t)kM * kE;          // fp32 [M,4]
constexpr size_t WS_W1HI  = WS_PROBS + (size_t)kM * kE;          // bf16 [D,D]
constexpr size_t WS_W1LO  = WS_W1HI + (size_t)kD * kD / 2;       // bf16 [D,D]
constexpr size_t WS_OWB   = WS_W1LO + (size_t)kD * kD / 2;       // bf16 [1280,D]
constexpr size_t WS_SUMS  = WS_OWB + (size_t)kCLSP * kD / 2;
constexpr size_t WS_SUMSQ = WS_SUMS + kD;
constexpr size_t WS_CNT   = WS_SUMSQ + kD;
constexpr size_t WS_AA    = WS_CNT + 1;
constexpr size_t WS_CC    = WS_AA + kD;
constexpr int WS_ZERON = (int)(2 * kD + 1);    // SUMS, SUMSQ, CNT

typedef __attribute__((ext_vector_type(8))) short short8;
typedef __attribute__((ext_vector_type(4))) float f32x4;

#define GLOBAL_LOAD_LDS16(gp, lp)                                          \
  __builtin_amdgcn_global_load_lds(                                        \
      (const __attribute__((address_space(1))) void*)(gp),                 \
      (__attribute__((address_space(3))) void*)(lp), 16, 0, 0)

__device__ __forceinline__ float block_reduce_sum(float v, float* red) {
  const int tid = threadIdx.x;
  __syncthreads();
  red[tid] = v;
  __syncthreads();
  for (int s = 128; s > 0; s >>= 1) {
    if (tid < s) red[tid] += red[tid + s];
    __syncthreads();
  }
  return red[0];
}

__device__ __forceinline__ float block_reduce_max(float v, float* red) {
  const int tid = threadIdx.x;
  __syncthreads();
  red[tid] = v;
  __syncthreads();
  for (int s = 128; s > 0; s >>= 1) {
    if (tid < s) red[tid] = fmaxf(red[tid], red[tid + s]);
    __syncthreads();
  }
  return red[0];
}

__global__ void k_zero(float* __restrict__ p, int n) {
  int i = blockIdx.x * 256 + threadIdx.x;
  if (i < n) p[i] = 0.f;
}

// zero sentinel rows (t=-1, t=T) of Hpad and Y1pad
__global__ void k_zero_bnd(__hip_bfloat16* __restrict__ Hpad,
                           __hip_bfloat16* __restrict__ Y1pad) {
  const int b = blockIdx.x >> 1;
  const int row = b * kTP + ((blockIdx.x & 1) ? (kTP - 1) : 0);
  const __hip_bfloat16 z = __float2bfloat16(0.f);
  for (int d = threadIdx.x; d < kD; d += 256) Hpad[(size_t)row * kD + d] = z;
  for (int d = threadIdx.x; d < kFF; d += 256) Y1pad[(size_t)row * kFF + d] = z;
}

// fp32 -> (hi, lo) bf16 split; 4 elems/thread
__global__ __launch_bounds__(256) void k_split(const float* __restrict__ src,
                                               __hip_bfloat16* __restrict__ hi,
                                               __hip_bfloat16* __restrict__ lo,
                                               int n4) {
  const int i = blockIdx.x * 256 + threadIdx.x;
  if (i >= n4) return;
  const float4 v = *reinterpret_cast<const float4*>(src + (size_t)i * 4);
  const float vv[4] = {v.x, v.y, v.z, v.w};
  unsigned short h[4], l[4];
#pragma unroll
  for (int j = 0; j < 4; ++j) {
    __hip_bfloat16 hb = __float2bfloat16(vv[j]);
    __hip_bfloat16 lb = __float2bfloat16(vv[j] - __bfloat162float(hb));
    h[j] = *reinterpret_cast<unsigned short*>(&hb);
    l[j] = *reinterpret_cast<unsigned short*>(&lb);
  }
  *reinterpret_cast<short4*>(hi + (size_t)i * 4) =
      make_short4(h[0], h[1], h[2], h[3]);
  *reinterpret_cast<short4*>(lo + (size_t)i * 4) =
      make_short4(l[0], l[1], l[2], l[3]);
}

// out_w [1200,D] fp32 -> OWB [1280,D] bf16, zero padded rows
__global__ __launch_bounds__(256) void k_wcast_pad(
    const float* __restrict__ w, __hip_bfloat16* __restrict__ dst) {
  const size_t i = (size_t)blockIdx.x * 256 + threadIdx.x;
  if (i >= (size_t)kCLSP * kD) return;
  const size_t r = i / kD;
  dst[i] = __float2bfloat16(r < kCLS ? w[i] : 0.f);
}

// conv weight transpose+cast: src [O][I][3] fp32 -> dst [3][O][I] bf16
__global__ __launch_bounds__(256) void k_wt(const float* __restrict__ src,
                                            __hip_bfloat16* __restrict__ dst,
                                            int n) {
  const int i = blockIdx.x * 256 + threadIdx.x;
  if (i >= n) return;
  const float* s = src + (size_t)i * 3;
  dst[i] = __float2bfloat16(s[0]);
  dst[(size_t)n + i] = __float2bfloat16(s[1]);
  dst[(size_t)2 * n + i] = __float2bfloat16(s[2]);
}

// ----- fc1: H = (Xhi+Xlo) @ (Whi+Wlo)^T + b, via hi*hi + lo*hi + hi*lo -----
__global__ __launch_bounds__(256) void k_fc1_mfma(
    const __hip_bfloat16* __restrict__ Xhi, const __hip_bfloat16* __restrict__ Xlo,
    const __hip_bfloat16* __restrict__ Whi, const __hip_bfloat16* __restrict__ Wlo,
    const float* __restrict__ bias, float* __restrict__ H) {
  __shared__ __align__(16) __hip_bfloat16 As[128 * 32];
  __shared__ __align__(16) __hip_bfloat16 Bs[128 * 32];
  const int tid = threadIdx.x;
  const int m0 = blockIdx.y * 128;
  const int n0 = blockIdx.x * 128;
  const int w = tid >> 6, lane = tid & 63;
  const int wm = (w >> 1) * 64, wn = (w & 1) * 64;
  f32x4 acc[4][4] = {};
  const int fr = lane & 15, fc = (lane >> 4) * 8;
  const __hip_bfloat16* Aps[3] = {Xhi, Xlo, Xhi};
  const __hip_bfloat16* Bps[3] = {Whi, Whi, Wlo};
  for (int p = 0; p < 3; ++p) {
    const __hip_bfloat16* Ab = Aps[p] + (size_t)m0 * kD;
    const __hip_bfloat16* Bb = Bps[p] + (size_t)n0 * kD;
    for (int k0 = 0; k0 < kD; k0 += 32) {
      __syncthreads();
#pragma unroll
      for (int r = 0; r < 2; ++r) {
        const int idx = r * 256 + tid;
        const int row = idx >> 2, cg = (idx & 3) * 8;
        GLOBAL_LOAD_LDS16(Ab + (size_t)row * kD + k0 + cg, &As[idx * 8]);
        GLOBAL_LOAD_LDS16(Bb + (size_t)row * kD + k0 + cg, &Bs[idx * 8]);
      }
      __syncthreads();
      short8 af[4], bf[4];
#pragma unroll
      for (int i = 0; i < 4; ++i) {
        af[i] = *reinterpret_cast<const short8*>(&As[(wm + i * 16 + fr) * 32 + fc]);
        bf[i] = *reinterpret_cast<const short8*>(&Bs[(wn + i * 16 + fr) * 32 + fc]);
      }
#pragma unroll
      for (int i = 0; i < 4; ++i)
#pragma unroll
        for (int j = 0; j < 4; ++j)
          acc[i][j] = __builtin_amdgcn_mfma_f32_16x16x32_bf16(af[i], bf[j], acc[i][j], 0, 0, 0);
    }
  }
  const int cr = (lane >> 4) * 4, cc = lane & 15;
#pragma unroll
  for (int i = 0; i < 4; ++i) {
#pragma unroll
    for (int r = 0; r < 4; ++r) {
      const int m = m0 + wm + i * 16 + cr + r;
#pragma unroll
      for (int j = 0; j < 4; ++j) {
        const int gc = n0 + wn + j * 16 + cc;
        H[(size_t)m * kD + gc] = acc[i][j][r] + bias[gc];
      }
    }
  }
}

// ----- classifier: logits = featb @ OWB^T + out_b (N padded to 1280) -----
__global__ __launch_bounds__(256) void k_cls_mfma(
    const __hip_bfloat16* __restrict__ Fb, const __hip_bfloat16* __restrict__ Wb,
    const float* __restrict__ bias, float* __restrict__ logits) {
  __shared__ __align__(16) __hip_bfloat16 As[128 * 32];
  __shared__ __align__(16) __hip_bfloat16 Bs[128 * 32];
  const int tid = threadIdx.x;
  const int m0 = blockIdx.y * 128;
  const int n0 = blockIdx.x * 128;
  const int w = tid >> 6, lane = tid & 63;
  const int wm = (w >> 1) * 64, wn = (w & 1) * 64;
  f32x4 acc[4][4] = {};
  const int fr = lane & 15, fc = (lane >> 4) * 8;
  const __hip_bfloat16* Ab = Fb + (size_t)m0 * kD;
  const __hip_bfloat16* Bb = Wb + (size_t)n0 * kD;
  for (int k0 = 0; k0 < kD; k0 += 32) {
    __syncthreads();
#pragma unroll
    for (int r = 0; r < 2; ++r) {
      const int idx = r * 256 + tid;
      const int row = idx >> 2, cg = (idx & 3) * 8;
      GLOBAL_LOAD_LDS16(Ab + (size_t)row * kD + k0 + cg, &As[idx * 8]);
      GLOBAL_LOAD_LDS16(Bb + (size_t)row * kD + k0 + cg, &Bs[idx * 8]);
    }
    __syncthreads();
    short8 af[4], bf[4];
#pragma unroll
    for (int i = 0; i < 4; ++i) {
      af[i] = *reinterpret_cast<const short8*>(&As[(wm + i * 16 + fr) * 32 + fc]);
      bf[i] = *reinterpret_cast<const short8*>(&Bs[(wn + i * 16 + fr) * 32 + fc]);
    }
#pragma unroll
    for (int i = 0; i < 4; ++i)
#pragma unroll
      for (int j = 0; j < 4; ++j)
        acc[i][j] = __builtin_amdgcn_mfma_f32_16x16x32_bf16(af[i], bf[j], acc[i][j], 0, 0, 0);
  }
  const int cr = (lane >> 4) * 4, cc = lane & 15;
#pragma unroll
  for (int i = 0; i < 4; ++i) {
#pragma unroll
    for (int r = 0; r < 4; ++r) {
      const int m = m0 + wm + i * 16 + cr + r;
#pragma unroll
      for (int j = 0; j < 4; ++j) {
        const int gc = n0 + wn + j * 16 + cc;
        if (gc < kCLS) logits[(size_t)m * kCLS + gc] = acc[i][j][r] + bias[gc];
      }
    }
  }
}

// ----- MFMA conv kernels (unchanged from round 2) -----
__global__ __launch_bounds__(256) void k_conv1_mfma(
    const __hip_bfloat16* __restrict__ Hpad, const __hip_bfloat16* __restrict__ W1T,
    const float* __restrict__ b1, __hip_bfloat16* __restrict__ Y1pad) {
  __shared__ __align__(16) __hip_bfloat16 As[128 * 32];
  __shared__ __align__(16) __hip_bfloat16 Bs[128 * 32];
  const int tid = threadIdx.x;
  const int m0 = blockIdx.y * 128;
  const int n0 = blockIdx.x * 128;
  const int b = m0 >> 9;
  const int t0 = m0 & (kT - 1);
  const int arow0 = b * kTP + t0;
  const int w = tid >> 6, lane = tid & 63;
  const int wm = (w >> 1) * 64, wn = (w & 1) * 64;
  f32x4 acc[4][4] = {};
  const int fr = lane & 15, fc = (lane >> 4) * 8;
  for (int kk = 0; kk < 3; ++kk) {
    const __hip_bfloat16* Ab = Hpad + (size_t)(arow0 + kk) * kD;
    const __hip_bfloat16* Bb = W1T + (size_t)kk * kFF * kD + (size_t)n0 * kD;
    for (int k0 = 0; k0 < kD; k0 += 32) {
      __syncthreads();
#pragma unroll
      for (int r = 0; r < 2; ++r) {
        const int idx = r * 256 + tid;
        const int row = idx >> 2, cg = (idx & 3) * 8;
        GLOBAL_LOAD_LDS16(Ab + (size_t)row * kD + k0 + cg, &As[idx * 8]);
        GLOBAL_LOAD_LDS16(Bb + (size_t)row * kD + k0 + cg, &Bs[idx * 8]);
      }
      __syncthreads();
      short8 af[4], bf[4];
#pragma unroll
      for (int i = 0; i < 4; ++i) {
        af[i] = *reinterpret_cast<const short8*>(&As[(wm + i * 16 + fr) * 32 + fc]);
        bf[i] = *reinterpret_cast<const short8*>(&Bs[(wn + i * 16 + fr) * 32 + fc]);
      }
#pragma unroll
      for (int i = 0; i < 4; ++i)
#pragma unroll
        for (int j = 0; j < 4; ++j)
          acc[i][j] = __builtin_amdgcn_mfma_f32_16x16x32_bf16(af[i], bf[j], acc[i][j], 0, 0, 0);
    }
  }
  const int orow0 = b * kTP + t0 + 1;
  const int cr = (lane >> 4) * 4, cc = lane & 15;
#pragma unroll
  for (int i = 0; i < 4; ++i) {
#pragma unroll
    for (int r = 0; r < 4; ++r) {
      const int lr = wm + i * 16 + cr + r;
#pragma unroll
      for (int j = 0; j < 4; ++j) {
        const int gc = n0 + wn + j * 16 + cc;
        const float v = acc[i][j][r] + b1[gc];
        Y1pad[(size_t)(orow0 + lr) * kFF + gc] = __float2bfloat16(fmaxf(v, 0.f));
      }
    }
  }
}

__global__ __launch_bounds__(256) void k_conv2_mfma(
    const __hip_bfloat16* __restrict__ Y1pad, const __hip_bfloat16* __restrict__ W2T,
    const float* __restrict__ b2, const float* __restrict__ gates,
    int e, float* __restrict__ moe) {
  __shared__ __align__(16) __hip_bfloat16 As[128 * 32];
  __shared__ __align__(16) __hip_bfloat16 Bs[128 * 32];
  const int tid = threadIdx.x;
  const int m0 = blockIdx.y * 128;
  const int n0 = blockIdx.x * 128;
  const int b = m0 >> 9;
  const int t0 = m0 & (kT - 1);
  const int arow0 = b * kTP + t0;
  const int w = tid >> 6, lane = tid & 63;
  const int wm = (w >> 1) * 64, wn = (w & 1) * 64;
  f32x4 acc[4][4] = {};
  const int fr = lane & 15, fc = (lane >> 4) * 8;
  for (int kk = 0; kk < 3; ++kk) {
    const __hip_bfloat16* Ab = Y1pad + (size_t)(arow0 + kk) * kFF;
    const __hip_bfloat16* Bb = W2T + (size_t)kk * kD * kFF + (size_t)n0 * kFF;
    for (int k0 = 0; k0 < kFF; k0 += 32) {
      __syncthreads();
#pragma unroll
      for (int r = 0; r < 2; ++r) {
        const int idx = r * 256 + tid;
        const int row = idx >> 2, cg = (idx & 3) * 8;
        GLOBAL_LOAD_LDS16(Ab + (size_t)row * kFF + k0 + cg, &As[idx * 8]);
        GLOBAL_LOAD_LDS16(Bb + (size_t)row * kFF + k0 + cg, &Bs[idx * 8]);
      }
      __syncthreads();
      short8 af[4], bf[4];
#pragma unroll
      for (int i = 0; i < 4; ++i) {
        af[i] = *reinterpret_cast<const short8*>(&As[(wm + i * 16 + fr) * 32 + fc]);
        bf[i] = *reinterpret_cast<const short8*>(&Bs[(wn + i * 16 + fr) * 32 + fc]);
      }
#pragma unroll
      for (int i = 0; i < 4; ++i)
#pragma unroll
        for (int j = 0; j < 4; ++j)
          acc[i][j] = __builtin_amdgcn_mfma_f32_16x16x32_bf16(af[i], bf[j], acc[i][j], 0, 0, 0);
    }
  }
  const int cr = (lane >> 4) * 4, cc = lane & 15;
#pragma unroll
  for (int i = 0; i < 4; ++i) {
#pragma unroll
    for (int r = 0; r < 4; ++r) {
      const int lr = wm + i * 16 + cr + r;
      const int m = m0 + lr;
      const float g = gates[(size_t)m * kE + e];
#pragma unroll
      for (int j = 0; j < 4; ++j) {
        const int gc = n0 + wn + j * 16 + cc;
        const float v = acc[i][j][r] + b2[gc];
        const size_t idx = (size_t)m * kD + gc;
        moe[idx] = (e == 0 ? 0.f : moe[idx]) + g * v;
      }
    }
  }
}

// ----- small kernels -----
__global__ __launch_bounds__(256) void k_cnt(const int* __restrict__ mask,
                                             float* __restrict__ cnt) {
  __shared__ float red[256];
  const int i = blockIdx.x * 256 + threadIdx.x;
  float v = (float)mask[i];
  v = block_reduce_sum(v, red);
  if (threadIdx.x == 0) atomicAdd(cnt, v);
}

__global__ __launch_bounds__(256) void k_stats(const float* __restrict__ H,
                                               const int* __restrict__ mask,
                                               float* __restrict__ sums,
                                               float* __restrict__ sumsq) {
  const int ch = blockIdx.x * 256 + threadIdx.x;
  const int r0 = blockIdx.y * 256;
  float s = 0.f, q = 0.f;
  for (int r = r0; r < r0 + 256; ++r) {
    if (mask[r]) {
      const float v = H[(size_t)r * kD + ch];
      s += v;
      q += v * v;
    }
  }
  atomicAdd(&sums[ch], s);
  atomicAdd(&sumsq[ch], q);
}

__global__ __launch_bounds__(256) void k_finalize(
    const float* __restrict__ sums, const float* __restrict__ sumsq,
    const float* __restrict__ cntp, const float* __restrict__ bn_g,
    const float* __restrict__ bn_b, float* __restrict__ aa,
    float* __restrict__ cc) {
  const int d = blockIdx.x * 256 + threadIdx.x;
  const float cnt = fmaxf(*cntp, 1.f);
  const float mean = sums[d] / cnt;
  const float var = sumsq[d] / cnt - mean * mean;
  const float istd = rsqrtf(var + 1e-5f);
  const float a = bn_g[d] * istd;
  aa[d] = a;
  cc[d] = bn_b[d] - mean * a;
}

// masked BN + relu + pe -> Hpad (bf16); gate softmax/top2 -> gates, probs
__global__ __launch_bounds__(256) void k_norm_gate(
    const float* __restrict__ H, const int* __restrict__ mask,
    const float* __restrict__ pe, const float* __restrict__ aa,
    const float* __restrict__ cc, const float* __restrict__ gw,
    __hip_bfloat16* __restrict__ Hpad, float* __restrict__ gates,
    float* __restrict__ probs) {
  __shared__ float red[256];
  __shared__ float glog[4];
  const int r = blockIdx.x;
  const int tid = threadIdx.x;
  const int b = r >> 9;
  const int t = r & (kT - 1);
  const bool mv = mask[r] != 0;
  const size_t orow = (size_t)(b * kTP + t + 1) * kD;
  float gl[4] = {0.f, 0.f, 0.f, 0.f};
#pragma unroll
  for (int j = 0; j < 4; ++j) {
    const int d = tid + j * 256;
    float v = H[(size_t)r * kD + d];
    if (mv) v = v * aa[d] + cc[d];
    v = fmaxf(v, 0.f) + pe[(size_t)t * kD + d];
    Hpad[orow + d] = __float2bfloat16(v);
    const float4 g = *reinterpret_cast<const float4*>(gw + (size_t)d * 4);
    gl[0] += v * g.x; gl[1] += v * g.y; gl[2] += v * g.z; gl[3] += v * g.w;
  }
  for (int e = 0; e < 4; ++e) {
    const float s = block_reduce_sum(gl[e], red);
    if (tid == 0) glog[e] = s;
  }
  __syncthreads();
  if (tid == 0) {
    float lg[4] = {glog[0], glog[1], glog[2], glog[3]};
    const float mx = fmaxf(fmaxf(lg[0], lg[1]), fmaxf(lg[2], lg[3]));
    float ex[4], s = 0.f;
#pragma unroll
    for (int e = 0; e < 4; ++e) { ex[e] = expf(lg[e] - mx); s += ex[e]; }
    int i0 = 0;
    for (int e = 1; e < 4; ++e) if (lg[e] > lg[i0]) i0 = e;
    int i1 = -1;
    for (int e = 0; e < 4; ++e) {
      if (e == i0) continue;
      if (i1 < 0 || lg[e] > lg[i1]) i1 = e;
    }
    const float g0 = 1.f / (1.f + expf(lg[i1] - lg[i0]));
    float gv[4] = {0.f, 0.f, 0.f, 0.f};
    gv[i0] = g0;
    gv[i1] = 1.f - g0;
    *reinterpret_cast<float4*>(gates + (size_t)r * 4) =
        make_float4(gv[0], gv[1], gv[2], gv[3]);
    const float inv_s = 1.f / s;
    *reinterpret_cast<float4*>(probs + (size_t)r * 4) =
        make_float4(ex[0] * inv_s, ex[1] * inv_s, ex[2] * inv_s, ex[3] * inv_s);
  }
}

__global__ __launch_bounds__(256) void k_ln(
    const float* __restrict__ moe, const float* __restrict__ g,
    const float* __restrict__ b, float* __restrict__ feat,
    float* __restrict__ featn, __hip_bfloat16* __restrict__ featb) {
  __shared__ float red[256];
  const int r = blockIdx.x;
  const int tid = threadIdx.x;
  float v[4];
  float s = 0.f, q = 0.f;
#pragma unroll
  for (int j = 0; j < 4; ++j) {
    v[j] = moe[(size_t)r * kD + tid + j * 256];
    s += v[j];
    q += v[j] * v[j];
  }
  const float sum = block_reduce_sum(s, red);
  const float mu = sum * (1.f / kD);
  const float sq = block_reduce_sum(q, red);
  const float var = sq * (1.f / kD) - mu * mu;
  const float istd = rsqrtf(var + 1e-6f);
  float f[4];
  float fs = 0.f;
#pragma unroll
  for (int j = 0; j < 4; ++j) {
    const int d = tid + j * 256;
    f[j] = (v[j] - mu) * istd * g[d] + b[d];
    feat[(size_t)r * kD + d] = f[j];
    featb[(size_t)r * kD + d] = __float2bfloat16(f[j]);
    fs += f[j] * f[j];
  }
  const float nrm2 = block_reduce_sum(fs, red);
  const float scale = 1.f / fmaxf(sqrtf(nrm2), 1e-12f);
#pragma unroll
  for (int j = 0; j < 4; ++j) {
    const int d = tid + j * 256;
    featn[(size_t)r * kD + d] = f[j] * scale;
  }
}

__global__ __launch_bounds__(256) void k_softmax(
    const float* __restrict__ logits, float* __restrict__ logp,
    float* __restrict__ p) {
  __shared__ float red[256];
  const int r = blockIdx.x;
  const int tid = threadIdx.x;
  float lv[5];
  float mx = -1e30f;
#pragma unroll
  for (int j = 0; j < 5; ++j) {
    const int c = tid + j * 256;
    if (c < kCLS) {
      lv[j] = logits[(size_t)r * kCLS + c];
      mx = fmaxf(mx, lv[j]);
    }
  }
  mx = block_reduce_max(mx, red);
  float s = 0.f;
#pragma unroll
  for (int j = 0; j < 5; ++j) {
    const int c = tid + j * 256;
    if (c < kCLS) s += expf(lv[j] - mx);
  }
  s = block_reduce_sum(s, red);
  const float lse = mx + logf(s);
#pragma unroll
  for (int j = 0; j < 5; ++j) {
    const int c = tid + j * 256;
    if (c < kCLS) {
      const float lp = lv[j] - lse;
      logp[(size_t)r * kCLS + c] = lp;
      p[(size_t)r * kCLS + c] = expf(lp);
    }
  }
}

// aux = E * sum_e (frac_e * imp_e); single block, no global atomics
__global__ __launch_bounds__(256) void k_aux(const float* __restrict__ probs,
                                             const float* __restrict__ gates,
                                             float* __restrict__ out) {
  __shared__ float red[256];
  const int tid = threadIdx.x;
  float si[4] = {0.f, 0.f, 0.f, 0.f};
  float sf[4] = {0.f, 0.f, 0.f, 0.f};
  for (int i = tid; i < kM; i += 256) {
    const float4 p = *reinterpret_cast<const float4*>(probs + (size_t)i * 4);
    const float4 g = *reinterpret_cast<const float4*>(gates + (size_t)i * 4);
    si[0] += p.x; si[1] += p.y; si[2] += p.z; si[3] += p.w;
    sf[0] += (g.x > 0.f) ? 1.f : 0.f;
    sf[1] += (g.y > 0.f) ? 1.f : 0.f;
    sf[2] += (g.z > 0.f) ? 1.f : 0.f;
    sf[3] += (g.w > 0.f) ? 1.f : 0.f;
  }
  float tot = 0.f;
  for (int e = 0; e < 4; ++e) {
    const float S = block_reduce_sum(si[e], red);
    const float F = block_reduce_sum(sf[e], red);
    tot += (F / (float)kM) * (S / (float)kM);
  }
  if (tid == 0) out[0] = (float)kE * tot;
}

}  // namespace

extern "C" void kernel_launch(void* const* d_in, const int* in_sizes, int n_in,
                              void* d_out, int out_size, void* d_ws,
                              size_t ws_size, hipStream_t stream) {
  const float* x     = (const float*)d_in[0];
  const int*   mask  = (const int*)d_in[1];
  const float* fc1_w = (const float*)d_in[2];
  const float* fc1_b = (const float*)d_in[3];
  const float* bn_g  = (const float*)d_in[4];
  const float* bn_b  = (const float*)d_in[5];
  const float* pe    = (const float*)d_in[6];
  const float* gw    = (const float*)d_in[7];
  const float* ew1   = (const float*)d_in[8];
  const float* eb1   = (const float*)d_in[9];
  const float* ew2   = (const float*)d_in[10];
  const float* eb2   = (const float*)d_in[11];
  const float* ln_g  = (const float*)d_in[12];
  const float* ln_b  = (const float*)d_in[13];
  const float* out_w = (const float*)d_in[14];
  const float* out_b = (const float*)d_in[15];

  float* ws = (float*)d_ws;
  float* H     = ws + WS_H;                       // fc1 out; later MOE
  __hip_bfloat16* HPAD  = (__hip_bfloat16*)(ws + WS_HPAD);
  __hip_bfloat16* Y1PAD = (__hip_bfloat16*)(ws + WS_Y1P);
  // aliases of the Y1PAD region (disjoint lifetimes):
  __hip_bfloat16* XHI   = (__hip_bfloat16*)(ws + WS_Y1P);             // fc1 phase
  __hip_bfloat16* XLO   = XHI + kBTD;                                 // fc1 phase
  __hip_bfloat16* FEATB = (__hip_bfloat16*)(ws + WS_Y1P);             // epilogue
  __hip_bfloat16* W1T   = (__hip_bfloat16*)(ws + WS_W1T);
  __hip_bfloat16* W2T   = (__hip_bfloat16*)(ws + WS_W2T);
  float* GATES = ws + WS_GATES;
  float* PROBS = ws + WS_PROBS;
  __hip_bfloat16* W1HI = (__hip_bfloat16*)(ws + WS_W1HI);
  __hip_bfloat16* W1LO = (__hip_bfloat16*)(ws + WS_W1LO);
  __hip_bfloat16* OWB  = (__hip_bfloat16*)(ws + WS_OWB);
  float* SUMS  = ws + WS_SUMS;
  float* SUMSQ = ws + WS_SUMSQ;
  float* CNT   = ws + WS_CNT;
  float* AA    = ws + WS_AA;
  float* CC    = ws + WS_CC;
  float* MOE   = H;

  float* outf   = (float*)d_out;
  float* feat   = outf;
  float* featn  = outf + kBTD;
  float* logits = outf + 2 * kBTD;
  float* logp   = logits + kBTC;
  float* pprob  = logp + kBTC;
  float* aux    = pprob + kBTC;

  k_zero<<<dim3((WS_ZERON + 255) / 256), 256, 0, stream>>>(SUMS, WS_ZERON);
  // split x and fc1_w into bf16 hi/lo
  k_split<<<dim3((int)(kBTD / 4 + 255) / 256), 256, 0, stream>>>(x, XHI, XLO,
                                                                 (int)(kBTD / 4));
  k_split<<<dim3((kD * kD / 4 + 255) / 256), 256, 0, stream>>>(
      fc1_w, W1HI, W1LO, kD * kD / 4);
  // fc1 via 3-pass split-bf16 MFMA
  k_fc1_mfma<<<dim3(kD / 128, kM / 128), 256, 0, stream>>>(XHI, XLO, W1HI,
                                                           W1LO, fc1_b, H);
  // sentinel rows (after fc1: XHI/XLO alias Y1PAD)
  k_zero_bnd<<<dim3(2 * kB), 256, 0, stream>>>(HPAD, Y1PAD);
  k_cnt<<<dim3(kM / 256), 256, 0, stream>>>(mask, CNT);
  k_stats<<<dim3(kD / 256, kM / 256), 256, 0, stream>>>(H, mask, SUMS, SUMSQ);
  k_finalize<<<dim3(kD / 256), 256, 0, stream>>>(SUMS, SUMSQ, CNT, bn_g, bn_b,
                                                 AA, CC);
  k_norm_gate<<<dim3(kM), 256, 0, stream>>>(H, mask, pe, AA, CC, gw, HPAD,
                                            GATES, PROBS);
  for (int e = 0; e < kE; ++e) {
    k_wt<<<dim3((kFF * kD + 255) / 256), 256, 0, stream>>>(
        ew1 + (size_t)e * kFF * kD * 3, W1T, kFF * kD);
    k_wt<<<dim3((kD * kFF + 255) / 256), 256, 0, stream>>>(
        ew2 + (size_t)e * kD * kFF * 3, W2T, kD * kFF);
    k_conv1_mfma<<<dim3(kFF / 128, kM / 128), 256, 0, stream>>>(
        HPAD, W1T, eb1 + (size_t)e * kFF, Y1PAD);
    k_conv2_mfma<<<dim3(kD / 128, kM / 128), 256, 0, stream>>>(
        Y1PAD, W2T, eb2 + (size_t)e * kD, GATES, e, MOE);
  }
  k_ln<<<dim3(kM), 256, 0, stream>>>(MOE, ln_g, ln_b, feat, featn, FEATB);
  k_wcast_pad<<<dim3((int)((size_t)kCLSP * kD + 255) / 256), 256, 0, stream>>>(
      out_w, OWB);
  k_cls_mfma<<<dim3(kCLSP / 128, kM / 128), 256, 0, stream>>>(FEATB, OWB,
                                                              out_b, logits);
  k_softmax<<<dim3(kM), 256, 0, stream>>>(logits, logp, pprob);
  k_aux<<<1, 256, 0, stream>>>(PROBS, GATES, aux);
}